// Round 9
// baseline (167.022 us; speedup 1.0000x reference)
//
#include <hip/hip_runtime.h>
#include <hip/hip_bf16.h>

// Problem constants
#define B_   2
#define C_   32
#define D_   16
#define HW_  4096
#define CK_  4
#define E_   64    // CK_*D_  (qk dim)
#define M_   512   // C_*D_   (v dim)
#define JC_  4     // j-split factor (flash split-K)

typedef __attribute__((ext_vector_type(8)))  short bf16x8;
typedef __attribute__((ext_vector_type(16))) float f32x16;

union U4 { unsigned int u[4]; bf16x8 v; };

__device__ __forceinline__ short f2bf(float f) {
    __hip_bfloat16 h = __float2bfloat16(f);
    return *reinterpret_cast<short*>(&h);
}
__device__ __forceinline__ unsigned short f2bfu(float f) {
    __hip_bfloat16 h = __float2bfloat16(f);
    return *reinterpret_cast<unsigned short*>(&h);
}

// ---------------------------------------------------------------------------
// Kernel 0: build padded bf16 weight block Wall[64][32] + fp32 bias ball[64].
//   rows 0..31 = Wv, 32..35 = Wk, 36..39 = Wq, 40..63 = 0.   (VERBATIM R8)
// ---------------------------------------------------------------------------
__global__ void prep_kernel(
    const float* __restrict__ Wk, const float* __restrict__ bk,
    const float* __restrict__ Wq, const float* __restrict__ bq,
    const float* __restrict__ Wv, const float* __restrict__ bv,
    short* __restrict__ Wall, float* __restrict__ ball)
{
    int t = threadIdx.x;
    for (int i = t; i < 64*C_; i += 256) {
        int o = i >> 5, cc = i & 31;
        float val = (o < 32) ? Wv[o*C_ + cc]
                  : (o < 36) ? Wk[(o-32)*C_ + cc]
                  : (o < 40) ? Wq[(o-36)*C_ + cc] : 0.f;
        Wall[o*C_ + cc] = f2bf(val);
    }
    if (t < 64)
        ball[t] = (t < 32) ? bv[t] : (t < 36) ? bk[t-32] : (t < 40) ? bq[t-36] : 0.f;
}

// ---------------------------------------------------------------------------
// Kernel 1: MFMA projections.  (VERBATIM R8)
// ---------------------------------------------------------------------------
__global__ __launch_bounds__(256) void proj_kernel(
    const float* __restrict__ x,
    const short* __restrict__ Wall, const float* __restrict__ ball,
    short* __restrict__ xk, short* __restrict__ xq,
    __hip_bfloat16* __restrict__ v)
{
    __shared__ short s_k[32*16], s_q[32*16];   // [p 32][w*4+o' 16]
    const int t    = threadIdx.x;
    const int lane = t & 63;
    const int w    = t >> 6;
    const int h    = lane >> 5;
    const int c    = lane & 31;

    const int pt = blockIdx.x & 127;
    const int dg = (blockIdx.x >> 7) & 3;
    const int b  = blockIdx.x >> 9;
    const int d  = dg*4 + w;
    const int p0 = pt*32;

    bf16x8 af[2][2];
    #pragma unroll
    for (int mt = 0; mt < 2; ++mt)
        #pragma unroll
        for (int s = 0; s < 2; ++s)
            af[mt][s] = *(const bf16x8*)(Wall + (mt*32 + c)*C_ + s*16 + h*8);

    U4 xb[2];
    #pragma unroll
    for (int s = 0; s < 2; ++s) {
        #pragma unroll
        for (int j = 0; j < 4; ++j) {
            int c0 = s*16 + h*8 + 2*j;
            union { float f; unsigned int u; } ua, ub;
            ua.f = x[(((size_t)(b*C_ + c0  )*D_ + d)*HW_) + p0 + c];
            ub.f = x[(((size_t)(b*C_ + c0+1)*D_ + d)*HW_) + p0 + c];
            xb[s].u[j] = __builtin_amdgcn_perm(ub.u, ua.u, 0x07060302);
        }
    }

    f32x16 a0, a1;
    #pragma unroll
    for (int r = 0; r < 16; ++r) { a0[r] = 0.f; a1[r] = 0.f; }
    #pragma unroll
    for (int s = 0; s < 2; ++s) {
        a0 = __builtin_amdgcn_mfma_f32_32x32x16_bf16(af[0][s], xb[s].v, a0, 0, 0, 0);
        a1 = __builtin_amdgcn_mfma_f32_32x32x16_bf16(af[1][s], xb[s].v, a1, 0, 0, 0);
    }

    #pragma unroll
    for (int r = 0; r < 16; ++r) {
        int o = (r & 3) + 8*(r >> 2) + 4*h;
        v[((size_t)b*M_ + (o*D_ + d))*HW_ + p0 + c] = __float2bfloat16(a0[r] + ball[o]);
    }

    #pragma unroll
    for (int r = 0; r < 4; ++r) {
        if (h == 0) s_k[c*16 + w*4 + r] = f2bf(a1[r] + ball[32 + r]);
        else        s_q[c*16 + w*4 + r] = f2bf(a1[r] + ball[36 + r]);
    }
    __syncthreads();

    const int p = t >> 3, seg = t & 7;
    size_t gb = ((size_t)b*HW_ + p0 + p)*E_ + dg*16 + seg*2;
    *(unsigned int*)(xk + gb) = *(const unsigned int*)(&s_k[p*16 + seg*2]);
    *(unsigned int*)(xq + gb) = *(const unsigned int*)(&s_q[p*16 + seg*2]);
}

// ---------------------------------------------------------------------------
// Kernel 2: flash attention, split-K (JC_=4), V staged in LDS.
//  R9 change (the ONLY change vs R8): TJ 32 -> 64. Iteration count halves
//  (32 -> 16) to amortize the measured per-iter fixed cost (~1000 cyc of
//  barrier skew + vmcnt drain + phase waits; R5/R7/R8 all 76us at different
//  occupancies = latency-bound, not pipe-bound). The 64-wide tile is two
//  sequential 32-wide halves (jh) using R8's verified math verbatim.
//  LDS rows now 128B with 8-chunk XOR swizzle (slot = chunk ^ (row&7)).
//  grid = 8 cls x 16 ig x 4 jc = 512 = 2 blocks/CU; LDS 48KB.
// ---------------------------------------------------------------------------
__device__ __forceinline__ void load_lds16(const short* g, short* l) {
    __builtin_amdgcn_global_load_lds((const __attribute__((address_space(1))) void*)g,
                                     (__attribute__((address_space(3))) void*)l,
                                     16, 0, 0);
}

__global__ __launch_bounds__(256, 2) void attn_kernel(
    const short* __restrict__ xk_, const short* __restrict__ xq_,
    const short* __restrict__ v_,
    unsigned short* __restrict__ Op, float* __restrict__ lw)
{
    __shared__ short s_xq[2][4096];          // XQ tile: 64 j x 64 e      (16 KB)
    __shared__ short s_v [2][8192];          // V  tile: 128 m x 64 j     (32 KB)

    const int t    = threadIdx.x;
    const int lane = t & 63;
    const int w    = t >> 6;
    const int h    = lane >> 5;
    const int c    = lane & 31;

    const int cls  = blockIdx.x & 7;         // constant per XCD under %8 mapping
    const int b    = cls >> 2, mg = cls & 3;
    const int rest = blockIdx.x >> 3;
    const int ig   = rest & 15;
    const int jc   = rest >> 4;
    const int i0   = ig*256 + w*64;          // wave's 64-row i-tile (two halves)
    const int jbase = jc*(HW_/JC_);          // 1024-wide j chunk

    const short* xk_g = xk_ + (size_t)b*HW_*E_;
    const short* xq_g = xq_ + (size_t)b*HW_*E_;
    const short* v_g  = v_  + (size_t)b*M_*HW_ + (size_t)mg*128*HW_;

    // XK B-frags, both halves: kb[H][s] = XK[i0+H*32+c][e = s*16 + h*8 ..+7]
    bf16x8 kb[2][4];
    #pragma unroll
    for (int H = 0; H < 2; ++H)
        #pragma unroll
        for (int s = 0; s < 4; ++s)
            kb[H][s] = *(const bf16x8*)(xk_g + (size_t)(i0 + H*32 + c)*E_ + s*16 + h*8);

    f32x16 accA[4], accB[4];
    #pragma unroll
    for (int mt = 0; mt < 4; ++mt)
        #pragma unroll
        for (int r = 0; r < 16; ++r) { accA[mt][r] = 0.f; accB[mt][r] = 0.f; }
    float lpA = 0.f, lpB = 0.f;

    // ---- staging: 64-j tiles, 128B rows, 8-chunk XOR swizzle ----
    // XQ: 64 rows; wave w stages rows [w*16, w*16+16) in 2 instrs.
    // V: 128 rows; wave w stages rows [w*32, w*32+32) in 4 instrs.
    auto stage = [&](int buf, int j0) {
        #pragma unroll
        for (int kx = 0; kx < 2; ++kx) {
            int rb = w*16 + kx*8;
            int r_ = rb + (lane>>3), cc = (lane&7) ^ (r_&7);
            load_lds16(xq_g + (size_t)(j0 + r_)*E_ + cc*8, &s_xq[buf][rb*64]);
        }
        #pragma unroll
        for (int kv = 0; kv < 4; ++kv) {
            int rb = w*32 + kv*8;
            int r_ = rb + (lane>>3), cc = (lane&7) ^ (r_&7);
            load_lds16(v_g + (size_t)r_*HW_ + j0 + cc*8, &s_v[buf][rb*64]);
        }
    };

    stage(0, jbase);
    __syncthreads();

    constexpr int NIT = (HW_/JC_)/64;        // 16 iterations
    for (int it = 0; it < NIT; ++it) {
        const int cur = it & 1;
        if (it + 1 < NIT)
            stage(cur^1, jbase + (it+1)*64); // prefetch flies during compute

        #pragma unroll
        for (int jh = 0; jh < 2; ++jh) {
            // ST halves [32j x 32i], K=64 in 4 steps; a1 read shared by A and B
            f32x16 stA, stB;
            #pragma unroll
            for (int r = 0; r < 16; ++r) { stA[r] = 0.f; stB[r] = 0.f; }
            #pragma unroll
            for (int s = 0; s < 4; ++s) {
                int jr   = jh*32 + c;
                int slot = (s*2 + h) ^ (jr & 7);
                bf16x8 a1 = *(const bf16x8*)(&s_xq[cur][jr*64 + slot*8]);
                stA = __builtin_amdgcn_mfma_f32_32x32x16_bf16(a1, kb[0][s], stA, 0, 0, 0);
                stB = __builtin_amdgcn_mfma_f32_32x32x16_bf16(a1, kb[1][s], stB, 0, 0, 0);
            }

            // exp + pack bf16x2; j-half exchange via shfl_xor(32)
            unsigned int dqA[8], pdA[8], dqB[8], pdB[8];
            #pragma unroll
            for (int qd = 0; qd < 8; ++qd) {
                union { float f; unsigned int u; } ua, ub;
                float a0 = __expf(stA[2*qd]);
                float a1v = __expf(stA[2*qd+1]);
                lpA += a0 + a1v;
                ua.f = a0; ub.f = a1v;
                dqA[qd] = __builtin_amdgcn_perm(ub.u, ua.u, 0x07060302);
                float b0 = __expf(stB[2*qd]);
                float b1v = __expf(stB[2*qd+1]);
                lpB += b0 + b1v;
                ua.f = b0; ub.f = b1v;
                dqB[qd] = __builtin_amdgcn_perm(ub.u, ua.u, 0x07060302);
            }
            #pragma unroll
            for (int qd = 0; qd < 8; ++qd) {
                pdA[qd] = __shfl_xor(dqA[qd], 32, 64);
                pdB[qd] = __shfl_xor(dqB[qd], 32, 64);
            }

            // PV: 2 K-steps x 4 m-tiles; each vb read feeds BOTH i-halves
            #pragma unroll
            for (int s2 = 0; s2 < 2; ++s2) {
                U4 a2A, a2B;
                if (s2 == 0) {
                    a2A.u[0] = h ? pdA[2] : dqA[0];  a2B.u[0] = h ? pdB[2] : dqB[0];
                    a2A.u[1] = h ? pdA[3] : dqA[1];  a2B.u[1] = h ? pdB[3] : dqB[1];
                    a2A.u[2] = h ? dqA[2] : pdA[0];  a2B.u[2] = h ? dqB[2] : pdB[0];
                    a2A.u[3] = h ? dqA[3] : pdA[1];  a2B.u[3] = h ? dqB[3] : pdB[1];
                } else {
                    a2A.u[0] = h ? pdA[6] : dqA[4];  a2B.u[0] = h ? pdB[6] : dqB[4];
                    a2A.u[1] = h ? pdA[7] : dqA[5];  a2B.u[1] = h ? pdB[7] : dqB[5];
                    a2A.u[2] = h ? dqA[6] : pdA[4];  a2B.u[2] = h ? dqB[6] : pdB[4];
                    a2A.u[3] = h ? dqA[7] : pdA[5];  a2B.u[3] = h ? dqB[7] : pdB[5];
                }
                #pragma unroll
                for (int mt = 0; mt < 4; ++mt) {
                    int rowm = mt*32 + c;
                    int slot = (jh*4 + s2*2 + h) ^ (rowm & 7);
                    bf16x8 vb = *(const bf16x8*)(&s_v[cur][rowm*64 + slot*8]);
                    accA[mt] = __builtin_amdgcn_mfma_f32_32x32x16_bf16(a2A.v, vb, accA[mt], 0, 0, 0);
                    accB[mt] = __builtin_amdgcn_mfma_f32_32x32x16_bf16(a2B.v, vb, accB[mt], 0, 0, 0);
                }
            }
        }
        __syncthreads();                     // drains prefetch + buffer swap
    }

    // l partials: sum two j-halves; one writer per (jc,b,i)
    float lA = lpA + __shfl_xor(lpA, 32, 64);
    float lB = lpB + __shfl_xor(lpB, 32, 64);
    if (h == 0 && mg == 0) {
        lw[(size_t)(jc*B_ + b)*HW_ + i0 + c]      = lA;
        lw[(size_t)(jc*B_ + b)*HW_ + i0 + 32 + c] = lB;
    }

    // partial O (unnormalized) -> bf16 workspace [jc][b][m][i]
    const size_t opb = ((size_t)(jc*B_ + b)*M_ + mg*128)*HW_;
    #pragma unroll
    for (int mt = 0; mt < 4; ++mt) {
        size_t rb = opb + (size_t)(mt*32 + c)*HW_ + i0;
        #pragma unroll
        for (int g = 0; g < 4; ++g) {
            ushort4 s4;
            s4.x = f2bfu(accA[mt][4*g+0]);
            s4.y = f2bfu(accA[mt][4*g+1]);
            s4.z = f2bfu(accA[mt][4*g+2]);
            s4.w = f2bfu(accA[mt][4*g+3]);
            *(ushort4*)(Op + rb + 8*g + 4*h) = s4;
            s4.x = f2bfu(accB[mt][4*g+0]);
            s4.y = f2bfu(accB[mt][4*g+1]);
            s4.z = f2bfu(accB[mt][4*g+2]);
            s4.w = f2bfu(accB[mt][4*g+3]);
            *(ushort4*)(Op + rb + 32 + 8*g + 4*h) = s4;
        }
    }
}

// ---------------------------------------------------------------------------
// Kernel 3: combine j-split partials + residual epilogue. (VERBATIM R8.)
// ---------------------------------------------------------------------------
__global__ __launch_bounds__(256) void reduce_kernel(
    const float* __restrict__ x, const float* __restrict__ gamma_p,
    const unsigned short* __restrict__ Op, const float* __restrict__ lw,
    float* __restrict__ out)
{
    size_t idx = ((size_t)blockIdx.x*256 + threadIdx.x)*4;  // flat [b][m][i]
    int i = idx & (HW_-1);
    size_t bm = idx >> 12;
    int m = bm & (M_-1);
    int b = (int)(bm >> 9);

    float4 o = {0.f,0.f,0.f,0.f};
    float4 l = {0.f,0.f,0.f,0.f};
    #pragma unroll
    for (int jc = 0; jc < JC_; ++jc) {
        ushort4 ov = *(const ushort4*)(Op + ((size_t)(jc*B_ + b)*M_ + m)*HW_ + i);
        o.x += __uint_as_float((unsigned int)ov.x << 16);
        o.y += __uint_as_float((unsigned int)ov.y << 16);
        o.z += __uint_as_float((unsigned int)ov.z << 16);
        o.w += __uint_as_float((unsigned int)ov.w << 16);
        float4 lv = *(const float4*)(lw + (size_t)(jc*B_ + b)*HW_ + i);
        l.x += lv.x; l.y += lv.y; l.z += lv.z; l.w += lv.w;
    }
    const float gamma = gamma_p[0];
    float4 xv = *(const float4*)(x + idx);
    float4 r;
    r.x = gamma*xv.x + o.x / l.x;
    r.y = gamma*xv.y + o.y / l.y;
    r.z = gamma*xv.z + o.z / l.z;
    r.w = gamma*xv.w + o.w / l.w;
    *(float4*)(out + idx) = r;
}

// ---------------------------------------------------------------------------
extern "C" void kernel_launch(void* const* d_in, const int* in_sizes, int n_in,
                              void* d_out, int out_size, void* d_ws, size_t ws_size,
                              hipStream_t stream)
{
    const float* x     = (const float*)d_in[0];
    const float* Wk    = (const float*)d_in[1];
    const float* bk    = (const float*)d_in[2];
    const float* Wq    = (const float*)d_in[3];
    const float* bq    = (const float*)d_in[4];
    const float* Wv    = (const float*)d_in[5];
    const float* bv    = (const float*)d_in[6];
    const float* gamma = (const float*)d_in[7];
    float* out = (float*)d_out;

    char* ws = (char*)d_ws;
    short*          xk   = (short*)(ws);                            // 1 MB
    short*          xq   = (short*)(ws + (1<<20));                  // 1 MB
    short*          v    = (short*)(ws + (2<<20));                  // 8 MB
    short*          Wall = (short*)(ws + (10<<20));                 // 4 KB
    float*          ball = (float*)(ws + (10<<20) + 4096);          // 256 B
    unsigned short* Op   = (unsigned short*)(ws + (10<<20) + 8192); // 32 MB
    float*          lw   = (float*)(ws + (10<<20) + 8192
                                    + (size_t)JC_*B_*M_*HW_*2);     // 128 KB

    prep_kernel<<<1, 256, 0, stream>>>(Wk, bk, Wq, bq, Wv, bv, Wall, ball);
    proj_kernel<<<B_*(D_/4)*(HW_/32), 256, 0, stream>>>(x, Wall, ball, xk, xq,
                                                        (__hip_bfloat16*)v);
    attn_kernel<<<8*16*JC_, 256, 0, stream>>>(xk, xq, v, Op, lw);
    reduce_kernel<<<(B_*M_*HW_)/(256*4), 256, 0, stream>>>(x, gamma, Op, lw, out);
}